// Round 1
// baseline (8018.784 us; speedup 1.0000x reference)
//
#include <hip/hip_runtime.h>
#include <hip/hip_bf16.h>

typedef unsigned short u16;
typedef short short8 __attribute__((ext_vector_type(8)));
typedef float floatx4 __attribute__((ext_vector_type(4)));

#define BATCH 64
#define SEQT  256
#define DDIM  1024
#define HDIM  1024
#define GDIM  4096          // 4H
#define MROWS 16384         // B*T

// ---------- helpers ----------
__device__ __forceinline__ u16 f2bf(float f) {
  unsigned u = __builtin_bit_cast(unsigned, f);
  u += 0x7fffu + ((u >> 16) & 1u);
  return (u16)(u >> 16);
}
__device__ __forceinline__ float bf2f(u16 v) {
  unsigned u = ((unsigned)v) << 16;
  return __builtin_bit_cast(float, u);
}
__device__ __forceinline__ float xz2f(float v) { return v; }
__device__ __forceinline__ float xz2f(u16 v) { return bf2f(v); }

template <typename T> __device__ __forceinline__ T f2xz(float v);
template <> __device__ __forceinline__ float f2xz<float>(float v) { return v; }
template <> __device__ __forceinline__ u16 f2xz<u16>(float v) { return f2bf(v); }

__device__ __forceinline__ float sigm(float x) { return 1.0f / (1.0f + __expf(-x)); }
__device__ __forceinline__ float tanh_(float x) {
  float a = __expf(2.0f * fabsf(x));      // inf-safe: a=inf -> r=1
  float r = 1.0f - 2.0f / (a + 1.0f);
  return x >= 0.0f ? r : -r;
}

__device__ __forceinline__ void async16(const void* g, void* l) {
  __builtin_amdgcn_global_load_lds(
      (const __attribute__((address_space(1))) unsigned int*)g,
      (__attribute__((address_space(3))) unsigned int*)l, 16, 0, 0);
}

// device-scope sense-free barrier: monotonic counter, per-direction
__device__ __forceinline__ void grid_barrier(unsigned* bar, unsigned target) {
  __syncthreads();
  if (threadIdx.x == 0) {
    __threadfence();  // release: flush this CU/XCD writes to coherence point
    __hip_atomic_fetch_add(bar, 1u, __ATOMIC_RELAXED, __HIP_MEMORY_SCOPE_AGENT);
    unsigned v;
    do {
      __builtin_amdgcn_s_sleep(2);
      v = __hip_atomic_load(bar, __ATOMIC_RELAXED, __HIP_MEMORY_SCOPE_AGENT);
    } while (v < target);
    __threadfence();  // acquire: invalidate stale L1/L2
  }
  __syncthreads();
}

// ---------- kernel 1: x fp32 -> bf16 ----------
__global__ __launch_bounds__(256) void k_cvt_x(const float* __restrict__ in,
                                               u16* __restrict__ out) {
  long i = ((long)blockIdx.x * 256 + threadIdx.x) * 4;
  float4 v = *(const float4*)(in + i);
  u16 o0 = f2bf(v.x), o1 = f2bf(v.y), o2 = f2bf(v.z), o3 = f2bf(v.w);
  unsigned lo = (unsigned)o0 | ((unsigned)o1 << 16);
  unsigned hi = (unsigned)o2 | ((unsigned)o3 << 16);
  uint2 p; p.x = lo; p.y = hi;
  *(uint2*)(out + i) = p;
}

// ---------- kernel 2: transpose-convert [1024][4096] fp32 -> [4096][1024] bf16 ----------
__global__ __launch_bounds__(256) void k_tc(const float* __restrict__ S0, const float* __restrict__ S1,
                                            const float* __restrict__ S2, const float* __restrict__ S3,
                                            u16* __restrict__ D0, u16* __restrict__ D1,
                                            u16* __restrict__ D2, u16* __restrict__ D3) {
  const float* src; u16* dst;
  switch (blockIdx.z) {
    case 0: src = S0; dst = D0; break;
    case 1: src = S1; dst = D1; break;
    case 2: src = S2; dst = D2; break;
    default: src = S3; dst = D3; break;
  }
  __shared__ __align__(16) float tl[64][65];
  const int k0 = blockIdx.x * 64, n0 = blockIdx.y * 64;
  const int tid = threadIdx.x, col = tid & 63, rq = tid >> 6;
#pragma unroll
  for (int i = 0; i < 16; i++) {
    int r = i * 4 + rq;
    tl[r][col] = src[(long)(k0 + r) * GDIM + n0 + col];
  }
  __syncthreads();
#pragma unroll
  for (int i = 0; i < 16; i++) {
    int r = i * 4 + rq;
    dst[(long)(n0 + r) * DDIM + k0 + col] = f2bf(tl[col][r]);
  }
}

// ---------- kernel 3: projection GEMM  xz = x_bf16 @ W (+bias) ----------
// A [16384][1024] bf16 row-major, Bt [4096][1024] bf16 (pre-transposed W)
template <typename XZT>
__global__ __launch_bounds__(256) void k_gemm(const u16* __restrict__ A,
                                              const u16* __restrict__ BtF, const u16* __restrict__ BtB,
                                              const float* __restrict__ biasF, const float* __restrict__ biasB,
                                              XZT* __restrict__ xzF, XZT* __restrict__ xzB) {
  const u16* Bt = blockIdx.z ? BtB : BtF;
  const float* bias = blockIdx.z ? biasB : biasF;
  XZT* xz = blockIdx.z ? xzB : xzF;
  const int m0 = blockIdx.x * 128, n0 = blockIdx.y * 128;
  __shared__ __align__(16) u16 Al[128 * 32];
  __shared__ __align__(16) u16 Bl[128 * 32];
  const int tid = threadIdx.x, w = tid >> 6, l = tid & 63;
  const int wm = w & 1, wn = w >> 1;
  floatx4 acc[4][4];
#pragma unroll
  for (int i = 0; i < 4; i++)
#pragma unroll
    for (int j = 0; j < 4; j++) acc[i][j] = (floatx4)(0.0f);

  const int srow = w * 32 + (l >> 2);
  const char* Ag = (const char*)(A + (long)(m0 + srow) * DDIM) + (l & 3) * 16;
  const char* Bg = (const char*)(Bt + (long)(n0 + srow) * DDIM) + (l & 3) * 16;
  char* Asl = (char*)Al + w * 2048;
  char* Bsl = (char*)Bl + w * 2048;

  for (int kt = 0; kt < 32; kt++) {
    __syncthreads();
    async16(Ag, Asl);
    async16(Ag + 16 * 2048, Asl + 1024);
    async16(Bg, Bsl);
    async16(Bg + 16 * 2048, Bsl + 1024);
    Ag += 64; Bg += 64;
    __syncthreads();
    short8 af[4], bfr[4];
#pragma unroll
    for (int i = 0; i < 4; i++) {
      af[i]  = *(const short8*)(Al + (wm * 64 + i * 16 + (l & 15)) * 32 + (l >> 4) * 8);
      bfr[i] = *(const short8*)(Bl + (wn * 64 + i * 16 + (l & 15)) * 32 + (l >> 4) * 8);
    }
#pragma unroll
    for (int i = 0; i < 4; i++)
#pragma unroll
      for (int j = 0; j < 4; j++)
        acc[i][j] = __builtin_amdgcn_mfma_f32_16x16x32_bf16(af[i], bfr[j], acc[i][j], 0, 0, 0);
  }
  const int c = l & 15, q = l >> 4;
#pragma unroll
  for (int j = 0; j < 4; j++) {
    const int n = n0 + wn * 64 + j * 16 + c;
    const float bv = bias[n];
#pragma unroll
    for (int i = 0; i < 4; i++) {
      const long mb = (long)(m0 + wm * 64 + i * 16 + q * 4);
#pragma unroll
      for (int r = 0; r < 4; r++)
        xz[(mb + r) * GDIM + n] = f2xz<XZT>(acc[i][j][r] + bv);
    }
  }
}

// ---------- kernel 4: persistent LSTM recurrence (both directions) ----------
// 256 wgs: wg>>7 = dir, wg&127 = column group (8 h-cols). One grid barrier per step.
template <typename XZT>
__global__ __launch_bounds__(256, 2) void k_lstm(const XZT* __restrict__ xzF, const XZT* __restrict__ xzB,
                                                 const u16* __restrict__ UtF, const u16* __restrict__ UtB,
                                                 u16* __restrict__ hbuf, float* __restrict__ out,
                                                 unsigned* __restrict__ bar) {
  const int wg = blockIdx.x;
  const int dir = wg >> 7;
  const int wd = wg & 127;
  const int j0 = wd * 8;
  const int tid = threadIdx.x;
  const int wave = tid >> 6, l = tid & 63;
  const int c = l & 15, q = l >> 4;
  const u16* Ut = dir ? UtB : UtF;
  const XZT* xz = dir ? xzB : xzF;
  unsigned* mybar = bar + dir * 32;
  u16* hb = hbuf + (long)dir * (2 * BATCH * HDIM);

  __shared__ __align__(16) u16 U1[16 * 1032];   // g/o columns, padded rows
  __shared__ float zl[64][33];

  // stage U tile1 (g,o) into LDS
#pragma unroll
  for (int u8 = 0; u8 < 8; u8++) {
    int unit = u8 * 256 + tid;          // 2048 units of 8 elements
    int r = unit >> 7, kc = unit & 127;
    int zr = (r < 8) ? (2048 + j0 + r) : (3072 + j0 + (r - 8));
    short8 v = *(const short8*)(Ut + (long)zr * DDIM + kc * 8);
    *(short8*)(&U1[r * 1032 + kc * 8]) = v;
  }
  // U tile0 (i,f) into registers: 32 frags = 128 VGPRs
  const int zr0 = (c < 8) ? (j0 + c) : (1024 + j0 + (c - 8));
  const int zr1 = zr0 + 2048;
  short8 bU0[32];
#pragma unroll
  for (int kt = 0; kt < 32; kt++)
    bU0[kt] = *(const short8*)(Ut + (long)zr0 * DDIM + kt * 32 + q * 8);

  // elementwise ownership: thread -> (row eb, col pair jj,jj+1)
  const int eb = tid >> 2;
  const int jj = (tid & 3) * 2;
  // zero h parity 0
  *(unsigned*)(hb + eb * HDIM + j0 + jj) = 0u;
  float cs0 = 0.0f, cs1 = 0.0f;

  __syncthreads();

  unsigned target = 128;
  for (int s = 0; s < SEQT; s++, target += 128) {
    grid_barrier(mybar, target);
    const int p = s & 1;
    const int t = dir ? (SEQT - 1 - s) : s;

    // prefetch xz for epilogue
    float xv0[4], xv1[4];
#pragma unroll
    for (int r = 0; r < 4; r++) {
      const long row = ((long)(wave * 16 + q * 4 + r) * SEQT + t) * GDIM;
      xv0[r] = xz2f(xz[row + zr0]);
      xv1[r] = xz2f(xz[row + zr1]);
    }

    const u16* hr = hb + p * (BATCH * HDIM) + (wave * 16 + c) * HDIM + q * 8;
    floatx4 a0 = (floatx4)(0.0f), a1 = (floatx4)(0.0f);
#pragma unroll
    for (int kt = 0; kt < 32; kt++) {
      short8 av = *(const short8*)(hr + kt * 32);
      short8 b1 = *(const short8*)(&U1[c * 1032 + kt * 32 + q * 8]);
      a0 = __builtin_amdgcn_mfma_f32_16x16x32_bf16(av, bU0[kt], a0, 0, 0, 0);
      a1 = __builtin_amdgcn_mfma_f32_16x16x32_bf16(av, b1, a1, 0, 0, 0);
    }
#pragma unroll
    for (int r = 0; r < 4; r++) {
      const int m = wave * 16 + q * 4 + r;
      zl[m][c]      = a0[r] + xv0[r];
      zl[m][16 + c] = a1[r] + xv1[r];
    }
    __syncthreads();

    // gates
    float zi0 = zl[eb][jj],      zi1 = zl[eb][jj + 1];
    float zf0 = zl[eb][8 + jj],  zf1 = zl[eb][8 + jj + 1];
    float zg0 = zl[eb][16 + jj], zg1 = zl[eb][16 + jj + 1];
    float zo0 = zl[eb][24 + jj], zo1 = zl[eb][24 + jj + 1];
    float i0 = sigm(zi0), f0 = sigm(zf0), g0 = tanh_(zg0), o0 = sigm(zo0);
    float i1 = sigm(zi1), f1 = sigm(zf1), g1 = tanh_(zg1), o1 = sigm(zo1);
    cs0 = f0 * cs0 + i0 * g0;
    cs1 = f1 * cs1 + i1 * g1;
    float h0v = o0 * tanh_(cs0), h1v = o1 * tanh_(cs1);

    unsigned hpair = (unsigned)f2bf(h0v) | ((unsigned)f2bf(h1v) << 16);
    *(unsigned*)(hb + (1 - p) * (BATCH * HDIM) + eb * HDIM + j0 + jj) = hpair;
    float2 op = make_float2(h0v, h1v);
    *(float2*)(out + (long)eb * (SEQT * 2 * HDIM) + (long)t * (2 * HDIM) + dir * HDIM + j0 + jj) = op;
  }
}

// ---------- host ----------
extern "C" void kernel_launch(void* const* d_in, const int* in_sizes, int n_in,
                              void* d_out, int out_size, void* d_ws, size_t ws_size,
                              hipStream_t stream) {
  const float* x   = (const float*)d_in[0];
  const float* Wf  = (const float*)d_in[1];
  const float* Uf  = (const float*)d_in[2];
  const float* bf_ = (const float*)d_in[3];
  const float* Wb  = (const float*)d_in[4];
  const float* Ub  = (const float*)d_in[5];
  const float* bb  = (const float*)d_in[6];
  float* out = (float*)d_out;
  char* ws = (char*)d_ws;

  const size_t SZ_XBF = (size_t)MROWS * DDIM * 2;        // 32 MB
  const size_t SZ_WT  = (size_t)GDIM * DDIM * 2;         // 8 MB
  const size_t SZ_H   = (size_t)2 * 2 * BATCH * HDIM * 2;

  size_t off = 1024;                       // [0,1024) barrier counters
  u16* xbf = (u16*)(ws + off); off += SZ_XBF;
  u16* WtF = (u16*)(ws + off); off += SZ_WT;
  u16* WtB = (u16*)(ws + off); off += SZ_WT;
  u16* UtF = (u16*)(ws + off); off += SZ_WT;
  u16* UtB = (u16*)(ws + off); off += SZ_WT;
  u16* hb  = (u16*)(ws + off); off += SZ_H;
  size_t xz_off = (off + 1023) & ~(size_t)1023;

  const size_t XZ_F32 = (size_t)MROWS * GDIM * 4;        // 256 MB each
  const size_t XZ_BF  = (size_t)MROWS * GDIM * 2;        // 128 MB each
  const bool fp32xz = ws_size >= xz_off + 2 * XZ_F32;

  unsigned* bar = (unsigned*)ws;
  hipMemsetAsync(bar, 0, 1024, stream);
  k_cvt_x<<<MROWS * DDIM / 1024, 256, 0, stream>>>(x, xbf);
  k_tc<<<dim3(16, 64, 4), 256, 0, stream>>>(Wf, Uf, Wb, Ub, WtF, UtF, WtB, UtB);

  if (fp32xz) {
    float* xzF = (float*)(ws + xz_off);
    float* xzB = (float*)(ws + xz_off + XZ_F32);
    k_gemm<float><<<dim3(128, 32, 2), 256, 0, stream>>>(xbf, WtF, WtB, bf_, bb, xzF, xzB);
    k_lstm<float><<<256, 256, 0, stream>>>(xzF, xzB, UtF, UtB, hb, out, bar);
  } else {
    u16* xzF = (u16*)(ws + xz_off);
    u16* xzB = (u16*)(ws + xz_off + XZ_BF);
    k_gemm<u16><<<dim3(128, 32, 2), 256, 0, stream>>>(xbf, WtF, WtB, bf_, bb, xzF, xzB);
    k_lstm<u16><<<256, 256, 0, stream>>>(xzF, xzB, UtF, UtB, hb, out, bar);
  }
}

// Round 3
// 5926.537 us; speedup vs baseline: 1.3530x; 1.3530x over previous
//
#include <hip/hip_runtime.h>
#include <hip/hip_bf16.h>

typedef unsigned short u16;
typedef short short8 __attribute__((ext_vector_type(8)));
typedef float floatx4 __attribute__((ext_vector_type(4)));

#define BATCH 64
#define SEQT  256
#define DDIM  1024
#define HDIM  1024
#define GDIM  4096          // 4H
#define MROWS 16384         // B*T

// ---------- helpers ----------
__device__ __forceinline__ u16 f2bf(float f) {
  unsigned u = __builtin_bit_cast(unsigned, f);
  u += 0x7fffu + ((u >> 16) & 1u);
  return (u16)(u >> 16);
}
__device__ __forceinline__ float bf2f(u16 v) {
  unsigned u = ((unsigned)v) << 16;
  return __builtin_bit_cast(float, u);
}
__device__ __forceinline__ float xz2f(float v) { return v; }
__device__ __forceinline__ float xz2f(u16 v) { return bf2f(v); }

template <typename T> __device__ __forceinline__ T f2xz(float v);
template <> __device__ __forceinline__ float f2xz<float>(float v) { return v; }
template <> __device__ __forceinline__ u16 f2xz<u16>(float v) { return f2bf(v); }

__device__ __forceinline__ float sigm(float x) { return 1.0f / (1.0f + __expf(-x)); }
__device__ __forceinline__ float tanh_(float x) {
  float a = __expf(2.0f * fabsf(x));      // inf-safe: a=inf -> r=1
  float r = 1.0f - 2.0f / (a + 1.0f);
  return x >= 0.0f ? r : -r;
}

__device__ __forceinline__ void async16(const void* g, void* l) {
  __builtin_amdgcn_global_load_lds(
      (const __attribute__((address_space(1))) unsigned int*)g,
      (__attribute__((address_space(3))) unsigned int*)l, 16, 0, 0);
}

// RMW-free all-scan grid barrier (per direction, 128 wgs).
// Leader stores the epoch to its own arrival word (no contended RMW chain);
// wave 0 of EVERY wg scans all 128 arrival words (2 cachelines) until all
// reached the epoch. Symmetric: no master, no flag, no publication chain.
__device__ __forceinline__ void grid_barrier(unsigned* arrv, int wd, int l, unsigned epoch) {
  __syncthreads();
  if (threadIdx.x == 0) {
    __threadfence();  // release: make prior h-stores visible at coherence point
    __hip_atomic_store(arrv + wd, epoch, __ATOMIC_RELAXED, __HIP_MEMORY_SCOPE_AGENT);
  }
  if (threadIdx.x < 64) {
    unsigned a, b;
    do {
      __builtin_amdgcn_s_sleep(2);
      a = __hip_atomic_load(arrv + l,      __ATOMIC_RELAXED, __HIP_MEMORY_SCOPE_AGENT);
      b = __hip_atomic_load(arrv + 64 + l, __ATOMIC_RELAXED, __HIP_MEMORY_SCOPE_AGENT);
    } while (!__all(a >= epoch && b >= epoch));
    if (l == 0) __threadfence();  // acquire: invalidate stale L1 before h reads
  }
  __syncthreads();
}

// ---------- kernel 1: x fp32 -> bf16 ----------
__global__ __launch_bounds__(256) void k_cvt_x(const float* __restrict__ in,
                                               u16* __restrict__ out) {
  long i = ((long)blockIdx.x * 256 + threadIdx.x) * 4;
  float4 v = *(const float4*)(in + i);
  u16 o0 = f2bf(v.x), o1 = f2bf(v.y), o2 = f2bf(v.z), o3 = f2bf(v.w);
  unsigned lo = (unsigned)o0 | ((unsigned)o1 << 16);
  unsigned hi = (unsigned)o2 | ((unsigned)o3 << 16);
  uint2 p; p.x = lo; p.y = hi;
  *(uint2*)(out + i) = p;
}

// ---------- kernel 2: transpose-convert [1024][4096] fp32 -> [4096][1024] bf16 ----------
__global__ __launch_bounds__(256) void k_tc(const float* __restrict__ S0, const float* __restrict__ S1,
                                            const float* __restrict__ S2, const float* __restrict__ S3,
                                            u16* __restrict__ D0, u16* __restrict__ D1,
                                            u16* __restrict__ D2, u16* __restrict__ D3) {
  const float* src; u16* dst;
  switch (blockIdx.z) {
    case 0: src = S0; dst = D0; break;
    case 1: src = S1; dst = D1; break;
    case 2: src = S2; dst = D2; break;
    default: src = S3; dst = D3; break;
  }
  __shared__ __align__(16) float tl[64][65];
  const int k0 = blockIdx.x * 64, n0 = blockIdx.y * 64;
  const int tid = threadIdx.x, col = tid & 63, rq = tid >> 6;
#pragma unroll
  for (int i = 0; i < 16; i++) {
    int r = i * 4 + rq;
    tl[r][col] = src[(long)(k0 + r) * GDIM + n0 + col];
  }
  __syncthreads();
#pragma unroll
  for (int i = 0; i < 16; i++) {
    int r = i * 4 + rq;
    dst[(long)(n0 + r) * DDIM + k0 + col] = f2bf(tl[col][r]);
  }
}

// ---------- kernel 3: projection GEMM  xz = x_bf16 @ W (+bias) ----------
// A [16384][1024] bf16 row-major, Bt [4096][1024] bf16 (pre-transposed W)
template <typename XZT>
__global__ __launch_bounds__(256) void k_gemm(const u16* __restrict__ A,
                                              const u16* __restrict__ BtF, const u16* __restrict__ BtB,
                                              const float* __restrict__ biasF, const float* __restrict__ biasB,
                                              XZT* __restrict__ xzF, XZT* __restrict__ xzB) {
  const u16* Bt = blockIdx.z ? BtB : BtF;
  const float* bias = blockIdx.z ? biasB : biasF;
  XZT* xz = blockIdx.z ? xzB : xzF;
  const int m0 = blockIdx.x * 128, n0 = blockIdx.y * 128;
  __shared__ __align__(16) u16 Al[128 * 32];
  __shared__ __align__(16) u16 Bl[128 * 32];
  const int tid = threadIdx.x, w = tid >> 6, l = tid & 63;
  const int wm = w & 1, wn = w >> 1;
  floatx4 acc[4][4];
#pragma unroll
  for (int i = 0; i < 4; i++)
#pragma unroll
    for (int j = 0; j < 4; j++) acc[i][j] = (floatx4)(0.0f);

  const int srow = w * 32 + (l >> 2);
  const char* Ag = (const char*)(A + (long)(m0 + srow) * DDIM) + (l & 3) * 16;
  const char* Bg = (const char*)(Bt + (long)(n0 + srow) * DDIM) + (l & 3) * 16;
  char* Asl = (char*)Al + w * 2048;
  char* Bsl = (char*)Bl + w * 2048;

  for (int kt = 0; kt < 32; kt++) {
    __syncthreads();
    async16(Ag, Asl);
    async16(Ag + 16 * 2048, Asl + 1024);
    async16(Bg, Bsl);
    async16(Bg + 16 * 2048, Bsl + 1024);
    Ag += 64; Bg += 64;
    __syncthreads();
    short8 af[4], bfr[4];
#pragma unroll
    for (int i = 0; i < 4; i++) {
      af[i]  = *(const short8*)(Al + (wm * 64 + i * 16 + (l & 15)) * 32 + (l >> 4) * 8);
      bfr[i] = *(const short8*)(Bl + (wn * 64 + i * 16 + (l & 15)) * 32 + (l >> 4) * 8);
    }
#pragma unroll
    for (int i = 0; i < 4; i++)
#pragma unroll
      for (int j = 0; j < 4; j++)
        acc[i][j] = __builtin_amdgcn_mfma_f32_16x16x32_bf16(af[i], bfr[j], acc[i][j], 0, 0, 0);
  }
  const int c = l & 15, q = l >> 4;
#pragma unroll
  for (int j = 0; j < 4; j++) {
    const int n = n0 + wn * 64 + j * 16 + c;
    const float bv = bias[n];
#pragma unroll
    for (int i = 0; i < 4; i++) {
      const long mb = (long)(m0 + wm * 64 + i * 16 + q * 4);
#pragma unroll
      for (int r = 0; r < 4; r++)
        xz[(mb + r) * GDIM + n] = f2xz<XZT>(acc[i][j][r] + bv);
    }
  }
}

// ---------- kernel 4: persistent LSTM recurrence (both directions) ----------
// 256 wgs: wg>>7 = dir, wg&127 = column group (8 h-cols). One grid barrier per step.
template <typename XZT>
__global__ __launch_bounds__(256, 2) void k_lstm(const XZT* __restrict__ xzF, const XZT* __restrict__ xzB,
                                                 const u16* __restrict__ UtF, const u16* __restrict__ UtB,
                                                 u16* __restrict__ hbuf, float* __restrict__ out,
                                                 unsigned* __restrict__ bar) {
  const int wg = blockIdx.x;
  const int dir = wg >> 7;
  const int wd = wg & 127;
  const int j0 = wd * 8;
  const int tid = threadIdx.x;
  const int wave = tid >> 6, l = tid & 63;
  const int c = l & 15, q = l >> 4;
  const u16* Ut = dir ? UtB : UtF;
  const XZT* xz = dir ? xzB : xzF;
  unsigned* arrv = bar + dir * 128;          // 128 arrival words per direction
  u16* hb = hbuf + (long)dir * (2 * BATCH * HDIM);

  __shared__ __align__(16) u16 U1[16 * 1032];   // g/o columns, padded rows
  __shared__ float zl[64][33];

  // stage U tile1 (g,o) into LDS
#pragma unroll
  for (int u8 = 0; u8 < 8; u8++) {
    int unit = u8 * 256 + tid;          // 2048 units of 8 elements
    int r = unit >> 7, kc = unit & 127;
    int zr = (r < 8) ? (2048 + j0 + r) : (3072 + j0 + (r - 8));
    short8 v = *(const short8*)(Ut + (long)zr * DDIM + kc * 8);
    *(short8*)(&U1[r * 1032 + kc * 8]) = v;
  }
  // U tile0 (i,f) into registers: 32 frags = 128 VGPRs
  const int zr0 = (c < 8) ? (j0 + c) : (1024 + j0 + (c - 8));
  const int zr1 = zr0 + 2048;
  short8 bU0[32];
#pragma unroll
  for (int kt = 0; kt < 32; kt++)
    bU0[kt] = *(const short8*)(Ut + (long)zr0 * DDIM + kt * 32 + q * 8);

  // elementwise ownership: thread -> (row eb, col pair jj,jj+1)
  const int eb = tid >> 2;
  const int jj = (tid & 3) * 2;
  // zero h parity 0
  *(unsigned*)(hb + eb * HDIM + j0 + jj) = 0u;
  float cs0 = 0.0f, cs1 = 0.0f;

  __syncthreads();

  for (int s = 0; s < SEQT; s++) {
    grid_barrier(arrv, wd, l, (unsigned)(s + 1));
    const int p = s & 1;
    const int t = dir ? (SEQT - 1 - s) : s;

    // prefetch xz for epilogue
    float xv0[4], xv1[4];
#pragma unroll
    for (int r = 0; r < 4; r++) {
      const long row = ((long)(wave * 16 + q * 4 + r) * SEQT + t) * GDIM;
      xv0[r] = xz2f(xz[row + zr0]);
      xv1[r] = xz2f(xz[row + zr1]);
    }

    const u16* hr = hb + p * (BATCH * HDIM) + (wave * 16 + c) * HDIM + q * 8;
    floatx4 a0 = (floatx4)(0.0f), a1 = (floatx4)(0.0f);
#pragma unroll
    for (int kt = 0; kt < 32; kt++) {
      short8 av = *(const short8*)(hr + kt * 32);
      short8 b1 = *(const short8*)(&U1[c * 1032 + kt * 32 + q * 8]);
      a0 = __builtin_amdgcn_mfma_f32_16x16x32_bf16(av, bU0[kt], a0, 0, 0, 0);
      a1 = __builtin_amdgcn_mfma_f32_16x16x32_bf16(av, b1, a1, 0, 0, 0);
    }
#pragma unroll
    for (int r = 0; r < 4; r++) {
      const int m = wave * 16 + q * 4 + r;
      zl[m][c]      = a0[r] + xv0[r];
      zl[m][16 + c] = a1[r] + xv1[r];
    }
    __syncthreads();

    // gates
    float zi0 = zl[eb][jj],      zi1 = zl[eb][jj + 1];
    float zf0 = zl[eb][8 + jj],  zf1 = zl[eb][8 + jj + 1];
    float zg0 = zl[eb][16 + jj], zg1 = zl[eb][16 + jj + 1];
    float zo0 = zl[eb][24 + jj], zo1 = zl[eb][24 + jj + 1];
    float i0 = sigm(zi0), f0 = sigm(zf0), g0 = tanh_(zg0), o0 = sigm(zo0);
    float i1 = sigm(zi1), f1 = sigm(zf1), g1 = tanh_(zg1), o1 = sigm(zo1);
    cs0 = f0 * cs0 + i0 * g0;
    cs1 = f1 * cs1 + i1 * g1;
    float h0v = o0 * tanh_(cs0), h1v = o1 * tanh_(cs1);

    unsigned hpair = (unsigned)f2bf(h0v) | ((unsigned)f2bf(h1v) << 16);
    *(unsigned*)(hb + (1 - p) * (BATCH * HDIM) + eb * HDIM + j0 + jj) = hpair;
    float2 op = make_float2(h0v, h1v);
    *(float2*)(out + (long)eb * (SEQT * 2 * HDIM) + (long)t * (2 * HDIM) + dir * HDIM + j0 + jj) = op;
  }
}

// ---------- host ----------
extern "C" void kernel_launch(void* const* d_in, const int* in_sizes, int n_in,
                              void* d_out, int out_size, void* d_ws, size_t ws_size,
                              hipStream_t stream) {
  const float* x   = (const float*)d_in[0];
  const float* Wf  = (const float*)d_in[1];
  const float* Uf  = (const float*)d_in[2];
  const float* bf_ = (const float*)d_in[3];
  const float* Wb  = (const float*)d_in[4];
  const float* Ub  = (const float*)d_in[5];
  const float* bb  = (const float*)d_in[6];
  float* out = (float*)d_out;
  char* ws = (char*)d_ws;

  const size_t SZ_XBF = (size_t)MROWS * DDIM * 2;        // 32 MB
  const size_t SZ_WT  = (size_t)GDIM * DDIM * 2;         // 8 MB
  const size_t SZ_H   = (size_t)2 * 2 * BATCH * HDIM * 2;

  size_t off = 2048;                       // [0,2048) barrier arrival words
  u16* xbf = (u16*)(ws + off); off += SZ_XBF;
  u16* WtF = (u16*)(ws + off); off += SZ_WT;
  u16* WtB = (u16*)(ws + off); off += SZ_WT;
  u16* UtF = (u16*)(ws + off); off += SZ_WT;
  u16* UtB = (u16*)(ws + off); off += SZ_WT;
  u16* hb  = (u16*)(ws + off); off += SZ_H;
  size_t xz_off = (off + 1023) & ~(size_t)1023;

  const size_t XZ_F32 = (size_t)MROWS * GDIM * 4;        // 256 MB each
  const size_t XZ_BF  = (size_t)MROWS * GDIM * 2;        // 128 MB each
  const bool fp32xz = ws_size >= xz_off + 2 * XZ_F32;

  unsigned* bar = (unsigned*)ws;
  hipMemsetAsync(bar, 0, 2048, stream);
  k_cvt_x<<<MROWS * DDIM / 1024, 256, 0, stream>>>(x, xbf);
  k_tc<<<dim3(16, 64, 4), 256, 0, stream>>>(Wf, Uf, Wb, Ub, WtF, UtF, WtB, UtB);

  if (fp32xz) {
    float* xzF = (float*)(ws + xz_off);
    float* xzB = (float*)(ws + xz_off + XZ_F32);
    k_gemm<float><<<dim3(128, 32, 2), 256, 0, stream>>>(xbf, WtF, WtB, bf_, bb, xzF, xzB);
    k_lstm<float><<<256, 256, 0, stream>>>(xzF, xzB, UtF, UtB, hb, out, bar);
  } else {
    u16* xzF = (u16*)(ws + xz_off);
    u16* xzB = (u16*)(ws + xz_off + XZ_BF);
    k_gemm<u16><<<dim3(128, 32, 2), 256, 0, stream>>>(xbf, WtF, WtB, bf_, bb, xzF, xzB);
    k_lstm<u16><<<256, 256, 0, stream>>>(xzF, xzB, UtF, UtB, hb, out, bar);
  }
}

// Round 4
// 4457.781 us; speedup vs baseline: 1.7988x; 1.3295x over previous
//
#include <hip/hip_runtime.h>
#include <hip/hip_bf16.h>

typedef unsigned short u16;
typedef unsigned long long u64;
typedef short short8 __attribute__((ext_vector_type(8)));
typedef float floatx4 __attribute__((ext_vector_type(4)));

#define BATCH 64
#define SEQT  256
#define DDIM  1024
#define HDIM  1024
#define GDIM  4096          // 4H
#define MROWS 16384         // B*T

// ---------- helpers ----------
__device__ __forceinline__ u16 f2bf(float f) {
  unsigned u = __builtin_bit_cast(unsigned, f);
  u += 0x7fffu + ((u >> 16) & 1u);
  return (u16)(u >> 16);
}
__device__ __forceinline__ float bf2f(u16 v) {
  unsigned u = ((unsigned)v) << 16;
  return __builtin_bit_cast(float, u);
}
__device__ __forceinline__ float xz2f(float v) { return v; }
__device__ __forceinline__ float xz2f(u16 v) { return bf2f(v); }

template <typename T> __device__ __forceinline__ T f2xz(float v);
template <> __device__ __forceinline__ float f2xz<float>(float v) { return v; }
template <> __device__ __forceinline__ u16 f2xz<u16>(float v) { return f2bf(v); }

__device__ __forceinline__ float sigm(float x) { return 1.0f / (1.0f + __expf(-x)); }
__device__ __forceinline__ float tanh_(float x) {
  float a = __expf(2.0f * fabsf(x));      // inf-safe: a=inf -> r=1
  float r = 1.0f - 2.0f / (a + 1.0f);
  return x >= 0.0f ? r : -r;
}

__device__ __forceinline__ void async16(const void* g, void* l) {
  __builtin_amdgcn_global_load_lds(
      (const __attribute__((address_space(1))) unsigned int*)g,
      (__attribute__((address_space(3))) unsigned int*)l, 16, 0, 0);
}

// agent-scope (LLC-coherent) primitives for the h hand-off
__device__ __forceinline__ void st_agent(unsigned* p, unsigned v) {
  __hip_atomic_store(p, v, __ATOMIC_RELAXED, __HIP_MEMORY_SCOPE_AGENT);
}
__device__ __forceinline__ u64 ld_agent64(const u64* p) {
  return __hip_atomic_load(p, __ATOMIC_RELAXED, __HIP_MEMORY_SCOPE_AGENT);
}

// Fence-free grid barrier (per direction, 128 wgs).
// Ordering: __syncthreads() drains vmcnt (all h agent-stores complete at the
// LLC coherence point) before the leader's arrival store; pollers use
// agent-scope loads (LLC-direct, proven to observe remote stores in R3).
// h data itself is only ever accessed with agent-scope ops -> no L2 staleness
// -> no cache-maintenance fences needed anywhere.
__device__ __forceinline__ void grid_barrier(unsigned* arrv, int wd, int l, unsigned epoch) {
  __syncthreads();
  if (threadIdx.x == 0)
    __hip_atomic_store(arrv + wd, epoch, __ATOMIC_RELAXED, __HIP_MEMORY_SCOPE_AGENT);
  if (threadIdx.x < 64) {
    unsigned a, b;
    do {
      __builtin_amdgcn_s_sleep(2);
      a = __hip_atomic_load(arrv + l,      __ATOMIC_RELAXED, __HIP_MEMORY_SCOPE_AGENT);
      b = __hip_atomic_load(arrv + 64 + l, __ATOMIC_RELAXED, __HIP_MEMORY_SCOPE_AGENT);
    } while (!__all(a >= epoch && b >= epoch));
  }
  __syncthreads();
}

// ---------- kernel 1: x fp32 -> bf16 ----------
__global__ __launch_bounds__(256) void k_cvt_x(const float* __restrict__ in,
                                               u16* __restrict__ out) {
  long i = ((long)blockIdx.x * 256 + threadIdx.x) * 4;
  float4 v = *(const float4*)(in + i);
  u16 o0 = f2bf(v.x), o1 = f2bf(v.y), o2 = f2bf(v.z), o3 = f2bf(v.w);
  unsigned lo = (unsigned)o0 | ((unsigned)o1 << 16);
  unsigned hi = (unsigned)o2 | ((unsigned)o3 << 16);
  uint2 p; p.x = lo; p.y = hi;
  *(uint2*)(out + i) = p;
}

// ---------- kernel 2: transpose-convert [1024][4096] fp32 -> [4096][1024] bf16 ----------
__global__ __launch_bounds__(256) void k_tc(const float* __restrict__ S0, const float* __restrict__ S1,
                                            const float* __restrict__ S2, const float* __restrict__ S3,
                                            u16* __restrict__ D0, u16* __restrict__ D1,
                                            u16* __restrict__ D2, u16* __restrict__ D3) {
  const float* src; u16* dst;
  switch (blockIdx.z) {
    case 0: src = S0; dst = D0; break;
    case 1: src = S1; dst = D1; break;
    case 2: src = S2; dst = D2; break;
    default: src = S3; dst = D3; break;
  }
  __shared__ __align__(16) float tl[64][65];
  const int k0 = blockIdx.x * 64, n0 = blockIdx.y * 64;
  const int tid = threadIdx.x, col = tid & 63, rq = tid >> 6;
#pragma unroll
  for (int i = 0; i < 16; i++) {
    int r = i * 4 + rq;
    tl[r][col] = src[(long)(k0 + r) * GDIM + n0 + col];
  }
  __syncthreads();
#pragma unroll
  for (int i = 0; i < 16; i++) {
    int r = i * 4 + rq;
    dst[(long)(n0 + r) * DDIM + k0 + col] = f2bf(tl[col][r]);
  }
}

// ---------- kernel 3: projection GEMM  xz = x_bf16 @ W (+bias) ----------
// A [16384][1024] bf16 row-major, Bt [4096][1024] bf16 (pre-transposed W)
template <typename XZT>
__global__ __launch_bounds__(256) void k_gemm(const u16* __restrict__ A,
                                              const u16* __restrict__ BtF, const u16* __restrict__ BtB,
                                              const float* __restrict__ biasF, const float* __restrict__ biasB,
                                              XZT* __restrict__ xzF, XZT* __restrict__ xzB) {
  const u16* Bt = blockIdx.z ? BtB : BtF;
  const float* bias = blockIdx.z ? biasB : biasF;
  XZT* xz = blockIdx.z ? xzB : xzF;
  const int m0 = blockIdx.x * 128, n0 = blockIdx.y * 128;
  __shared__ __align__(16) u16 Al[128 * 32];
  __shared__ __align__(16) u16 Bl[128 * 32];
  const int tid = threadIdx.x, w = tid >> 6, l = tid & 63;
  const int wm = w & 1, wn = w >> 1;
  floatx4 acc[4][4];
#pragma unroll
  for (int i = 0; i < 4; i++)
#pragma unroll
    for (int j = 0; j < 4; j++) acc[i][j] = (floatx4)(0.0f);

  const int srow = w * 32 + (l >> 2);
  const char* Ag = (const char*)(A + (long)(m0 + srow) * DDIM) + (l & 3) * 16;
  const char* Bg = (const char*)(Bt + (long)(n0 + srow) * DDIM) + (l & 3) * 16;
  char* Asl = (char*)Al + w * 2048;
  char* Bsl = (char*)Bl + w * 2048;

  for (int kt = 0; kt < 32; kt++) {
    __syncthreads();
    async16(Ag, Asl);
    async16(Ag + 16 * 2048, Asl + 1024);
    async16(Bg, Bsl);
    async16(Bg + 16 * 2048, Bsl + 1024);
    Ag += 64; Bg += 64;
    __syncthreads();
    short8 af[4], bfr[4];
#pragma unroll
    for (int i = 0; i < 4; i++) {
      af[i]  = *(const short8*)(Al + (wm * 64 + i * 16 + (l & 15)) * 32 + (l >> 4) * 8);
      bfr[i] = *(const short8*)(Bl + (wn * 64 + i * 16 + (l & 15)) * 32 + (l >> 4) * 8);
    }
#pragma unroll
    for (int i = 0; i < 4; i++)
#pragma unroll
      for (int j = 0; j < 4; j++)
        acc[i][j] = __builtin_amdgcn_mfma_f32_16x16x32_bf16(af[i], bfr[j], acc[i][j], 0, 0, 0);
  }
  const int c = l & 15, q = l >> 4;
#pragma unroll
  for (int j = 0; j < 4; j++) {
    const int n = n0 + wn * 64 + j * 16 + c;
    const float bv = bias[n];
#pragma unroll
    for (int i = 0; i < 4; i++) {
      const long mb = (long)(m0 + wm * 64 + i * 16 + q * 4);
#pragma unroll
      for (int r = 0; r < 4; r++)
        xz[(mb + r) * GDIM + n] = f2xz<XZT>(acc[i][j][r] + bv);
    }
  }
}

// ---------- kernel 4: persistent LSTM recurrence (both directions) ----------
// 256 wgs: wg>>7 = dir, wg&127 = column group (8 h-cols). One grid barrier per step.
// h double-buffer lives at LLC scope only (agent-scope atomics both ways).
template <typename XZT>
__global__ __launch_bounds__(256, 1) void k_lstm(const XZT* __restrict__ xzF, const XZT* __restrict__ xzB,
                                                 const u16* __restrict__ UtF, const u16* __restrict__ UtB,
                                                 u16* __restrict__ hbuf, float* __restrict__ out,
                                                 unsigned* __restrict__ bar) {
  const int wg = blockIdx.x;
  const int dir = wg >> 7;
  const int wd = wg & 127;
  const int j0 = wd * 8;
  const int tid = threadIdx.x;
  const int wave = tid >> 6, l = tid & 63;
  const int c = l & 15, q = l >> 4;
  const u16* Ut = dir ? UtB : UtF;
  const XZT* xz = dir ? xzB : xzF;
  unsigned* arrv = bar + dir * 128;          // 128 arrival words per direction
  u16* hb = hbuf + (long)dir * (2 * BATCH * HDIM);

  __shared__ __align__(16) u16 U1[16 * 1032];   // g/o columns, padded rows
  __shared__ float zl[64][33];

  // stage U tile1 (g,o) into LDS
#pragma unroll
  for (int u8 = 0; u8 < 8; u8++) {
    int unit = u8 * 256 + tid;          // 2048 units of 8 elements
    int r = unit >> 7, kc = unit & 127;
    int zr = (r < 8) ? (2048 + j0 + r) : (3072 + j0 + (r - 8));
    short8 v = *(const short8*)(Ut + (long)zr * DDIM + kc * 8);
    *(short8*)(&U1[r * 1032 + kc * 8]) = v;
  }
  // U tile0 (i,f) into registers: 32 frags = 128 regs (AGPR side of unified file)
  const int zr0 = (c < 8) ? (j0 + c) : (1024 + j0 + (c - 8));
  const int zr1 = zr0 + 2048;
  short8 bU0[32];
#pragma unroll
  for (int kt = 0; kt < 32; kt++)
    bU0[kt] = *(const short8*)(Ut + (long)zr0 * DDIM + kt * 32 + q * 8);

  // elementwise ownership: thread -> (row eb, col pair jj,jj+1)
  const int eb = tid >> 2;
  const int jj = (tid & 3) * 2;
  // zero h parity 0 (agent store: visible at LLC, never dirty in L2)
  st_agent((unsigned*)(hb + eb * HDIM + j0 + jj), 0u);
  float cs0 = 0.0f, cs1 = 0.0f;

  // xz prefetch (no h dependency; issued before the barrier each step)
  float xv0[4], xv1[4];
  auto prefetch = [&](int s) {
    const int t = dir ? (SEQT - 1 - s) : s;
#pragma unroll
    for (int r = 0; r < 4; r++) {
      const long row = ((long)(wave * 16 + q * 4 + r) * SEQT + t) * GDIM;
      xv0[r] = xz2f(xz[row + zr0]);
      xv1[r] = xz2f(xz[row + zr1]);
    }
  };
  prefetch(0);

  union HS { u64 qd[2]; short8 v; };

  for (int s = 0; s < SEQT; s++) {
    grid_barrier(arrv, wd, l, (unsigned)(s + 1));
    const int p = s & 1;
    const int t = dir ? (SEQT - 1 - s) : s;

    // h row for this lane, parity p: LLC-direct reads, 16-deep pipeline
    const u64* hq = (const u64*)(hb + (long)p * (BATCH * HDIM) + (wave * 16 + c) * HDIM + q * 8);
    HS hv[16];
#pragma unroll
    for (int kt = 0; kt < 16; kt++) {
      hv[kt].qd[0] = ld_agent64(hq + kt * 8);
      hv[kt].qd[1] = ld_agent64(hq + kt * 8 + 1);
    }
    floatx4 a0 = (floatx4)(0.0f), a1 = (floatx4)(0.0f);
#pragma unroll
    for (int kt = 0; kt < 32; kt++) {
      short8 av = hv[kt & 15].v;
      if (kt < 16) {
        hv[kt].qd[0] = ld_agent64(hq + (kt + 16) * 8);
        hv[kt].qd[1] = ld_agent64(hq + (kt + 16) * 8 + 1);
      }
      short8 b1 = *(const short8*)(&U1[c * 1032 + kt * 32 + q * 8]);
      a0 = __builtin_amdgcn_mfma_f32_16x16x32_bf16(av, bU0[kt], a0, 0, 0, 0);
      a1 = __builtin_amdgcn_mfma_f32_16x16x32_bf16(av, b1, a1, 0, 0, 0);
    }
#pragma unroll
    for (int r = 0; r < 4; r++) {
      const int m = wave * 16 + q * 4 + r;
      zl[m][c]      = a0[r] + xv0[r];
      zl[m][16 + c] = a1[r] + xv1[r];
    }
    __syncthreads();

    // gates
    float zi0 = zl[eb][jj],      zi1 = zl[eb][jj + 1];
    float zf0 = zl[eb][8 + jj],  zf1 = zl[eb][8 + jj + 1];
    float zg0 = zl[eb][16 + jj], zg1 = zl[eb][16 + jj + 1];
    float zo0 = zl[eb][24 + jj], zo1 = zl[eb][24 + jj + 1];
    float i0 = sigm(zi0), f0 = sigm(zf0), g0 = tanh_(zg0), o0 = sigm(zo0);
    float i1 = sigm(zi1), f1 = sigm(zf1), g1 = tanh_(zg1), o1 = sigm(zo1);
    cs0 = f0 * cs0 + i0 * g0;
    cs1 = f1 * cs1 + i1 * g1;
    float h0v = o0 * tanh_(cs0), h1v = o1 * tanh_(cs1);

    unsigned hpair = (unsigned)f2bf(h0v) | ((unsigned)f2bf(h1v) << 16);
    st_agent((unsigned*)(hb + (long)(1 - p) * (BATCH * HDIM) + eb * HDIM + j0 + jj), hpair);
    float2 op = make_float2(h0v, h1v);
    *(float2*)(out + (long)eb * (SEQT * 2 * HDIM) + (long)t * (2 * HDIM) + dir * HDIM + j0 + jj) = op;

    // issue next step's xz loads now; they drain inside the next barrier
    if (s + 1 < SEQT) prefetch(s + 1);
  }
}

// ---------- host ----------
extern "C" void kernel_launch(void* const* d_in, const int* in_sizes, int n_in,
                              void* d_out, int out_size, void* d_ws, size_t ws_size,
                              hipStream_t stream) {
  const float* x   = (const float*)d_in[0];
  const float* Wf  = (const float*)d_in[1];
  const float* Uf  = (const float*)d_in[2];
  const float* bf_ = (const float*)d_in[3];
  const float* Wb  = (const float*)d_in[4];
  const float* Ub  = (const float*)d_in[5];
  const float* bb  = (const float*)d_in[6];
  float* out = (float*)d_out;
  char* ws = (char*)d_ws;

  const size_t SZ_XBF = (size_t)MROWS * DDIM * 2;        // 32 MB
  const size_t SZ_WT  = (size_t)GDIM * DDIM * 2;         // 8 MB
  const size_t SZ_H   = (size_t)2 * 2 * BATCH * HDIM * 2;

  size_t off = 2048;                       // [0,2048) barrier arrival words
  u16* xbf = (u16*)(ws + off); off += SZ_XBF;
  u16* WtF = (u16*)(ws + off); off += SZ_WT;
  u16* WtB = (u16*)(ws + off); off += SZ_WT;
  u16* UtF = (u16*)(ws + off); off += SZ_WT;
  u16* UtB = (u16*)(ws + off); off += SZ_WT;
  u16* hb  = (u16*)(ws + off); off += SZ_H;
  size_t xz_off = (off + 1023) & ~(size_t)1023;

  const size_t XZ_F32 = (size_t)MROWS * GDIM * 4;        // 256 MB each
  const size_t XZ_BF  = (size_t)MROWS * GDIM * 2;        // 128 MB each
  const bool fp32xz = ws_size >= xz_off + 2 * XZ_F32;

  unsigned* bar = (unsigned*)ws;
  hipMemsetAsync(bar, 0, 2048, stream);
  k_cvt_x<<<MROWS * DDIM / 1024, 256, 0, stream>>>(x, xbf);
  k_tc<<<dim3(16, 64, 4), 256, 0, stream>>>(Wf, Uf, Wb, Ub, WtF, UtF, WtB, UtB);

  if (fp32xz) {
    float* xzF = (float*)(ws + xz_off);
    float* xzB = (float*)(ws + xz_off + XZ_F32);
    k_gemm<float><<<dim3(128, 32, 2), 256, 0, stream>>>(xbf, WtF, WtB, bf_, bb, xzF, xzB);
    k_lstm<float><<<256, 256, 0, stream>>>(xzF, xzB, UtF, UtB, hb, out, bar);
  } else {
    u16* xzF = (u16*)(ws + xz_off);
    u16* xzB = (u16*)(ws + xz_off + XZ_BF);
    k_gemm<u16><<<dim3(128, 32, 2), 256, 0, stream>>>(xbf, WtF, WtB, bf_, bb, xzF, xzB);
    k_lstm<u16><<<256, 256, 0, stream>>>(xzF, xzB, UtF, UtB, hb, out, bar);
  }
}